// Round 1
// baseline (310.275 us; speedup 1.0000x reference)
//
#include <hip/hip_runtime.h>

#define MAX_SPIKE_TIME 100000.0f
#define EPSILON 1e-10f
#define K_IN 1025       // IN_SIZE + bias
#define M_OUT 1024
#define BATCH 64

// ---------------------------------------------------------------------------
// Kernel 1: stable rank-by-counting sort of each row of [X | bias=1.0].
// grid = (5, 64), block = 256. Block (c, b) ranks elements i = c*256+tid of
// row b. Stable tie-break (j < i) matches JAX's stable argsort.
// ---------------------------------------------------------------------------
__global__ void rank_kernel(const float* __restrict__ X,
                            float* __restrict__ sx,
                            int* __restrict__ sidx) {
    const int b = blockIdx.y;
    __shared__ float row[K_IN];
    // cooperative load of the full row (all blocks of this b load it; cheap)
    for (int i = threadIdx.x; i < K_IN - 1; i += blockDim.x)
        row[i] = X[b * (K_IN - 1) + i];
    if (threadIdx.x == 0) row[K_IN - 1] = 1.0f;  // bias spike time
    __syncthreads();

    const int i = blockIdx.x * blockDim.x + threadIdx.x;
    if (i >= K_IN) return;
    const float xi = row[i];
    int rank = 0;
#pragma unroll 4
    for (int j = 0; j < K_IN; ++j) {
        const float xj = row[j];
        rank += (xj < xi) || (xj == xi && j < i);
    }
    sx[b * K_IN + rank] = xi;
    sidx[b * K_IN + rank] = i;
}

// ---------------------------------------------------------------------------
// Kernel 2: per (b, m) sequential scan over sorted inputs.
// grid = (4, 64), block = 256: thread handles output neuron
// m = blockIdx.x*256 + tid of batch b = blockIdx.y.
// Rounding discipline: explicit __fadd_rn / __fmul_rn so the cumsums round
// identically to numpy (no FMA contraction); division is IEEE.
// ---------------------------------------------------------------------------
__global__ void snn_kernel(const float* __restrict__ W,
                           const float* __restrict__ sx,
                           const int* __restrict__ sidx,
                           float* __restrict__ out) {
    const int b = blockIdx.y;
    const int m = blockIdx.x * blockDim.x + threadIdx.x;

    __shared__ float xs_s[K_IN + 1];
    __shared__ int   idx_s[K_IN];

    const float* sxb = sx + b * K_IN;
    const int*   sib = sidx + b * K_IN;
    for (int k = threadIdx.x; k < K_IN; k += blockDim.x) {
        xs_s[k]  = sxb[k];
        idx_s[k] = sib[k];
    }
    if (threadIdx.x == 0) xs_s[K_IN] = MAX_SPIKE_TIME;  // next_x sentinel
    __syncthreads();

    float cw = 0.0f, cwt = 0.0f, best = MAX_SPIKE_TIME;
    for (int k = 0; k < K_IN; ++k) {
        const float x   = xs_s[k];
        const int   row = idx_s[k];
        const float w   = W[row * M_OUT + m];
        cw  = __fadd_rn(cw, w);
        cwt = __fadd_rn(cwt, __fmul_rn(w, x));
        float denom = __fadd_rn(cw, -1.0f);
        denom = fminf(fmaxf(denom, EPSILON), MAX_SPIKE_TIME);
        const float cand = cwt / denom;
        float o = (cw < 1.0f) ? MAX_SPIKE_TIME : cand;
        if (cand < x) o = MAX_SPIKE_TIME;
        if (o > xs_s[k + 1]) o = MAX_SPIKE_TIME;
        best = fminf(best, o);
    }
    out[b * M_OUT + m] = best;
}

extern "C" void kernel_launch(void* const* d_in, const int* in_sizes, int n_in,
                              void* d_out, int out_size, void* d_ws, size_t ws_size,
                              hipStream_t stream) {
    const float* X = (const float*)d_in[0];   // [64, 1024]
    const float* W = (const float*)d_in[1];   // [1025, 1024]
    float* out = (float*)d_out;               // [64, 1024]

    float* sx  = (float*)d_ws;                         // [64, 1025]
    int*   sidx = (int*)((char*)d_ws + BATCH * K_IN * sizeof(float));

    dim3 g1((K_IN + 255) / 256, BATCH);
    rank_kernel<<<g1, 256, 0, stream>>>(X, sx, sidx);

    dim3 g2(M_OUT / 256, BATCH);
    snn_kernel<<<g2, 256, 0, stream>>>(W, sx, sidx, out);
}

// Round 2
// 159.733 us; speedup vs baseline: 1.9425x; 1.9425x over previous
//
#include <hip/hip_runtime.h>
#include <math.h>

#define MAX_SPIKE_TIME 100000.0f
#define EPSILON 1e-10f
#define K_IN 1025       // IN_SIZE + bias
#define M_OUT 1024
#define BATCH 64

#define K_MAIN 1024     // chunked main loop covers k = 0..1023; k=1024 in epilogue
#define UNROLL 16
#define K_PADR 1028     // rank kernel row padded to multiple of 4

// ---------------------------------------------------------------------------
// Kernel 1: stable rank-by-counting sort of each row of [X | bias=1.0].
// grid = (5, 64), block = 256. Stable tie-break (j < i) matches argsort.
// Inner loop vectorized with LDS float4 reads; pads are +inf (rank-neutral).
// Writes sidx premultiplied by M_OUT (element offset into W's row).
// ---------------------------------------------------------------------------
__global__ __launch_bounds__(256) void rank_kernel(const float* __restrict__ X,
                                                   float* __restrict__ sx,
                                                   int* __restrict__ sidx) {
    const int b = blockIdx.y;
    __shared__ float row[K_PADR];
    for (int i = threadIdx.x; i < K_PADR; i += blockDim.x) {
        float v;
        if (i < K_IN - 1)       v = X[b * (K_IN - 1) + i];
        else if (i == K_IN - 1) v = 1.0f;                       // bias spike
        else                    v = __builtin_huge_valf();      // rank-neutral pad
        row[i] = v;
    }
    __syncthreads();

    const int i = blockIdx.x * blockDim.x + threadIdx.x;
    if (i >= K_IN) return;
    const float xi = row[i];
    int rank = 0;
#pragma unroll 4
    for (int j = 0; j < K_PADR; j += 4) {
        const float4 r = *(const float4*)&row[j];
        rank += (r.x < xi) || (r.x == xi && (j + 0) < i);
        rank += (r.y < xi) || (r.y == xi && (j + 1) < i);
        rank += (r.z < xi) || (r.z == xi && (j + 2) < i);
        rank += (r.w < xi) || (r.w == xi && (j + 3) < i);
    }
    sx[b * K_IN + rank]   = xi;
    sidx[b * K_IN + rank] = i * M_OUT;   // premultiplied row offset
}

// ---------------------------------------------------------------------------
// Kernel 2: per (b, m) sequential scan over sorted inputs, software-pipelined.
// grid = (4, 64), block = 256. Chunk of UNROLL W-loads prefetched into
// registers while the previous chunk is consumed — breaks the per-iteration
// LDS->addr->load->use latency chain that made round 1 543 cyc/iter.
// Rounding: __fadd_rn/__fmul_rn (no FMA contraction) + IEEE div == numpy
// cumsum order bit-for-bit.
// ---------------------------------------------------------------------------
__global__ __launch_bounds__(256) void snn_kernel(const float* __restrict__ W,
                                                  const float* __restrict__ sx,
                                                  const int* __restrict__ sidx,
                                                  float* __restrict__ out) {
    const int b = blockIdx.y;
    const int m = blockIdx.x * blockDim.x + threadIdx.x;

    __shared__ float xs_s[K_MAIN + UNROLL + 2];   // pads = MAX_SPIKE_TIME
    __shared__ int   idxb_s[K_MAIN + UNROLL];     // pads = 0 (harmless loads)

    const float* sxb = sx + b * K_IN;
    const int*   sib = sidx + b * K_IN;
    for (int k = threadIdx.x; k < K_MAIN + UNROLL; k += 256) {
        if (k < K_IN) { xs_s[k] = sxb[k]; idxb_s[k] = sib[k]; }
        else          { xs_s[k] = MAX_SPIKE_TIME; idxb_s[k] = 0; }
    }
    if (threadIdx.x == 0) {
        xs_s[K_MAIN + UNROLL]     = MAX_SPIKE_TIME;
        xs_s[K_MAIN + UNROLL + 1] = MAX_SPIKE_TIME;
    }
    __syncthreads();

    const float* Wm = W + m;

    float cw = 0.0f, cwt = 0.0f, best = MAX_SPIKE_TIME;

    float wcur[UNROLL];
#pragma unroll
    for (int u = 0; u < UNROLL; ++u) wcur[u] = Wm[idxb_s[u]];

    for (int k0 = 0; k0 < K_MAIN; k0 += UNROLL) {
        // prefetch next chunk (pads resolve to W[0..][m] — discarded)
        float wnxt[UNROLL];
#pragma unroll
        for (int u = 0; u < UNROLL; ++u) wnxt[u] = Wm[idxb_s[k0 + UNROLL + u]];

#pragma unroll
        for (int u = 0; u < UNROLL; ++u) {
            const float x  = xs_s[k0 + u];
            const float xn = xs_s[k0 + u + 1];
            const float w  = wcur[u];
            cw  = __fadd_rn(cw, w);
            cwt = __fadd_rn(cwt, __fmul_rn(w, x));
            float denom = fminf(fmaxf(__fadd_rn(cw, -1.0f), EPSILON), MAX_SPIKE_TIME);
            const float cand = cwt / denom;               // IEEE div, matches ref
            float o = (cw < 1.0f) ? MAX_SPIKE_TIME : cand;
            o = (cand < x)  ? MAX_SPIKE_TIME : o;
            o = (o > xn)    ? MAX_SPIKE_TIME : o;
            best = fminf(best, o);
        }
#pragma unroll
        for (int u = 0; u < UNROLL; ++u) wcur[u] = wnxt[u];
    }

    // epilogue: k = 1024 (wcur[0] was prefetched from the real idxb_s[1024])
    {
        const float x  = xs_s[K_MAIN];
        const float xn = xs_s[K_MAIN + 1];                // MAX sentinel
        const float w  = wcur[0];
        cw  = __fadd_rn(cw, w);
        cwt = __fadd_rn(cwt, __fmul_rn(w, x));
        float denom = fminf(fmaxf(__fadd_rn(cw, -1.0f), EPSILON), MAX_SPIKE_TIME);
        const float cand = cwt / denom;
        float o = (cw < 1.0f) ? MAX_SPIKE_TIME : cand;
        o = (cand < x)  ? MAX_SPIKE_TIME : o;
        o = (o > xn)    ? MAX_SPIKE_TIME : o;
        best = fminf(best, o);
    }

    out[b * M_OUT + m] = best;
}

extern "C" void kernel_launch(void* const* d_in, const int* in_sizes, int n_in,
                              void* d_out, int out_size, void* d_ws, size_t ws_size,
                              hipStream_t stream) {
    const float* X = (const float*)d_in[0];   // [64, 1024]
    const float* W = (const float*)d_in[1];   // [1025, 1024]
    float* out = (float*)d_out;               // [64, 1024]

    float* sx   = (float*)d_ws;                                      // [64, 1025]
    int*   sidx = (int*)((char*)d_ws + BATCH * K_IN * sizeof(float)); // [64, 1025]

    dim3 g1((K_IN + 255) / 256, BATCH);
    rank_kernel<<<g1, 256, 0, stream>>>(X, sx, sidx);

    dim3 g2(M_OUT / 256, BATCH);
    snn_kernel<<<g2, 256, 0, stream>>>(W, sx, sidx, out);
}

// Round 3
// 156.068 us; speedup vs baseline: 1.9881x; 1.0235x over previous
//
#include <hip/hip_runtime.h>
#include <math.h>

#define MAX_SPIKE_TIME 100000.0f
#define EPSILON 1e-10f
#define K_IN 1025       // IN_SIZE + bias
#define M_OUT 1024
#define BATCH 64

#define K_MAIN 1024     // chunked main loop covers k = 0..1023; k=1024 in epilogue
#define UNROLL 16
#define K_PADR 1028     // rank row padded to multiple of 4

// ---------------------------------------------------------------------------
// Kernel 1: stable rank via branchless 64-bit key compares.
// key = (float_bits(x) << 11) | index  — positive floats order like their bit
// patterns, and the index low-bits give the stable tie-break (j < i) exactly.
// rank_i = #{ j : key_j < key_i }. One v_cmp_lt_u64 + add per element,
// no branches (round-2's short-circuit ||/&& compare is the suspected 78 µs).
// Pads are +inf keys (always greater -> contribute 0).
// ---------------------------------------------------------------------------
__global__ __launch_bounds__(256) void rank_kernel(const float* __restrict__ X,
                                                   float* __restrict__ sx,
                                                   int* __restrict__ sidx) {
    const int b = blockIdx.y;
    __shared__ __align__(16) unsigned long long keys[K_PADR];
    for (int i = threadIdx.x; i < K_PADR; i += 256) {
        float v;
        if (i < K_IN - 1)       v = X[b * (K_IN - 1) + i];
        else if (i == K_IN - 1) v = 1.0f;                       // bias spike
        else                    v = __builtin_huge_valf();      // rank-neutral pad
        keys[i] = ((unsigned long long)__float_as_uint(v) << 11) | (unsigned)i;
    }
    __syncthreads();

    const int i = blockIdx.x * blockDim.x + threadIdx.x;
    if (i >= K_IN) return;
    const unsigned long long ki = keys[i];
    int rank = 0;
#pragma unroll 4
    for (int j = 0; j < K_PADR; j += 2) {
        const ulonglong2 kk = *(const ulonglong2*)&keys[j];   // ds_read_b128
        rank += (int)(kk.x < ki);
        rank += (int)(kk.y < ki);
    }
    const float xi = __uint_as_float((unsigned)(ki >> 11));
    sx[b * K_IN + rank]   = xi;
    sidx[b * K_IN + rank] = i * M_OUT;   // premultiplied row offset into W
}

// ---------------------------------------------------------------------------
// Kernel 2: per (b, m) sequential scan, software-pipelined, DIVISION-FREE
// hot loop. cand = cwt/denom is only compared (denom > 0 whenever cw >= 1),
// so: valid  <=>  (cw>=1) & (cwt >= x*denom) & (cwt <= xn*denom).
// Running min kept as a fraction (bn/bd); cross-multiply compare; single
// IEEE div in the epilogue reproduces the ref's fl(cwt/denom) exactly for
// the winning candidate. cw/cwt cumsums stay bit-identical to numpy
// (__fadd_rn/__fmul_rn, no FMA contraction), so the cw<1 gate is unchanged.
// ---------------------------------------------------------------------------
__global__ __launch_bounds__(256) void snn_kernel(const float* __restrict__ W,
                                                  const float* __restrict__ sx,
                                                  const int* __restrict__ sidx,
                                                  float* __restrict__ out) {
    const int b = blockIdx.y;
    const int m = blockIdx.x * blockDim.x + threadIdx.x;

    __shared__ float xs_s[K_MAIN + UNROLL + 2];   // pads = MAX_SPIKE_TIME
    __shared__ int   idxb_s[K_MAIN + UNROLL];     // pads = 0 (harmless loads)

    const float* sxb = sx + b * K_IN;
    const int*   sib = sidx + b * K_IN;
    for (int k = threadIdx.x; k < K_MAIN + UNROLL; k += 256) {
        if (k < K_IN) { xs_s[k] = sxb[k]; idxb_s[k] = sib[k]; }
        else          { xs_s[k] = MAX_SPIKE_TIME; idxb_s[k] = 0; }
    }
    if (threadIdx.x == 0) {
        xs_s[K_MAIN + UNROLL]     = MAX_SPIKE_TIME;
        xs_s[K_MAIN + UNROLL + 1] = MAX_SPIKE_TIME;
    }
    __syncthreads();

    const float* Wm = W + m;

    float cw = 0.0f, cwt = 0.0f;
    float bn = MAX_SPIKE_TIME, bd = 1.0f;   // best candidate as fraction bn/bd

    float wcur[UNROLL];
#pragma unroll
    for (int u = 0; u < UNROLL; ++u) wcur[u] = Wm[idxb_s[u]];

    for (int k0 = 0; k0 < K_MAIN; k0 += UNROLL) {
        // prefetch next chunk (pads resolve to W[0..][m] — discarded)
        float wnxt[UNROLL];
#pragma unroll
        for (int u = 0; u < UNROLL; ++u) wnxt[u] = Wm[idxb_s[k0 + UNROLL + u]];

#pragma unroll
        for (int u = 0; u < UNROLL; ++u) {
            const float x  = xs_s[k0 + u];
            const float xn = xs_s[k0 + u + 1];
            const float w  = wcur[u];
            cw  = __fadd_rn(cw, w);
            cwt = __fadd_rn(cwt, __fmul_rn(w, x));
            const float denom = fmaxf(__fadd_rn(cw, -1.0f), EPSILON);
            const int valid = (int)(cw >= 1.0f)
                            & (int)(cwt >= __fmul_rn(x, denom))
                            & (int)(cwt <= __fmul_rn(xn, denom));
            const int better = valid
                             & (int)(__fmul_rn(cwt, bd) < __fmul_rn(bn, denom));
            bn = better ? cwt   : bn;
            bd = better ? denom : bd;
        }
#pragma unroll
        for (int u = 0; u < UNROLL; ++u) wcur[u] = wnxt[u];
    }

    // epilogue: k = 1024 (wcur[0] holds W for the real idxb_s[1024])
    {
        const float x  = xs_s[K_MAIN];
        const float xn = xs_s[K_MAIN + 1];                // MAX sentinel
        const float w  = wcur[0];
        cw  = __fadd_rn(cw, w);
        cwt = __fadd_rn(cwt, __fmul_rn(w, x));
        const float denom = fmaxf(__fadd_rn(cw, -1.0f), EPSILON);
        const int valid = (int)(cw >= 1.0f)
                        & (int)(cwt >= __fmul_rn(x, denom))
                        & (int)(cwt <= __fmul_rn(xn, denom));
        const int better = valid
                         & (int)(__fmul_rn(cwt, bd) < __fmul_rn(bn, denom));
        bn = better ? cwt   : bn;
        bd = better ? denom : bd;
    }

    out[b * M_OUT + m] = bn / bd;   // single IEEE div == ref's fl(cwt/denom)
}

extern "C" void kernel_launch(void* const* d_in, const int* in_sizes, int n_in,
                              void* d_out, int out_size, void* d_ws, size_t ws_size,
                              hipStream_t stream) {
    const float* X = (const float*)d_in[0];   // [64, 1024]
    const float* W = (const float*)d_in[1];   // [1025, 1024]
    float* out = (float*)d_out;               // [64, 1024]

    float* sx   = (float*)d_ws;                                       // [64, 1025]
    int*   sidx = (int*)((char*)d_ws + BATCH * K_IN * sizeof(float)); // [64, 1025]

    dim3 g1((K_IN + 255) / 256, BATCH);
    rank_kernel<<<g1, 256, 0, stream>>>(X, sx, sidx);

    dim3 g2(M_OUT / 256, BATCH);
    snn_kernel<<<g2, 256, 0, stream>>>(W, sx, sidx, out);
}